// Round 6
// baseline (42.641 us; speedup 1.0000x reference)
//
#include <hip/hip_runtime.h>

#define LD4(p) (*reinterpret_cast<const float4*>(p))

__device__ __forceinline__ float dot16(float4 e0, float4 e1, float4 e2, float4 e3,
                                       float4 w0, float4 w1, float4 w2, float4 w3) {
    return e0.x*w0.x + e0.y*w0.y + e0.z*w0.z + e0.w*w0.w
         + e1.x*w1.x + e1.y*w1.y + e1.z*w1.z + e1.w*w1.w
         + e2.x*w2.x + e2.y*w2.y + e2.z*w2.z + e2.w*w2.w
         + e3.x*w3.x + e3.y*w3.y + e3.z*w3.z + e3.w*w3.w;
}

__device__ __forceinline__ float redgrp16(float q) {
    q += __shfl_xor(q, 8, 16);
    q += __shfl_xor(q, 4, 16);
    q += __shfl_xor(q, 2, 16);
    q += __shfl_xor(q, 1, 16);
    return q;   // all 16 lanes of the group hold the full sum (a copy each)
}

__device__ __forceinline__ float bce_term(float q, float y, float m) {
    return m * (fmaxf(q, 0.0f) - q * y + __logf(1.0f + __expf(-fabsf(q))));
}

__global__ __launch_bounds__(256, 4) void hs_main(
    const float* __restrict__ emb,        // [N, 256]
    const float* __restrict__ fc,         // [V-1, 256]
    const int*   __restrict__ target,     // [N]
    const int*   __restrict__ path_idx,   // [V, L]
    const float* __restrict__ path_codes, // [V, L]
    const float* __restrict__ path_mask,  // [V, L]
    unsigned int* __restrict__ count,     // zeroed via memsetAsync each call
    float2* __restrict__ partials,        // [nblocks]
    float*  __restrict__ out,
    int N, int L, int nblocks)
{
    const int lane = threadIdx.x & 63;
    const int g    = lane >> 4;           // group 0..3 (one row each)
    const int li   = lane & 15;           // lane within group
    const int wid  = threadIdx.x >> 6;
    const int gwave = blockIdx.x * (blockDim.x >> 6) + wid;
    const int row  = gwave * 4 + g;

    float bce_acc = 0.0f;   // per-lane copy of the group's bce sum
    float cnt_acc = 0.0f;   // per-lane pm sum (exact)

    const int   srow   = (row < N) ? row : 0;
    const float rvalid = (row < N) ? 1.0f : 0.0f;

    // embedding slice: lane li holds floats [li*16, li*16+15]
    const float* erow = emb + (size_t)srow * 256 + li * 16;
    const float4 e0 = LD4(erow), e1 = LD4(erow + 4), e2 = LD4(erow + 8), e3 = LD4(erow + 12);
    const int t = target[srow];

    for (int base = 0; base < L; base += 16) {
        // chunk metadata: lane li holds entry base+li of this row's path
        int pi = 0; float pc = 0.0f, pm = 0.0f;
        const int mp = base + li;
        if (mp < L) {
            const size_t mo = (size_t)t * L + mp;
            pi = path_idx[mo];
            pc = path_codes[mo];
            pm = path_mask[mo] * rvalid;
        }
        const unsigned long long bal = __ballot(pm != 0.0f);
        if (bal == 0ull) break;                       // all 4 rows exhausted
        unsigned int or4 = (unsigned int)(bal | (bal >> 32));
        or4 |= or4 >> 16; or4 &= 0xFFFFu;             // OR of the 4 group prefixes
        const int kmax  = __popc(or4);                // longest remaining path in wave
        const int kquad = (kmax + 3) & ~3;            // pad to quads (entries are 0-safe)
        cnt_acc += pm;

        for (int k = 0; k < kquad; k += 4) {
            const int n0 = __shfl(pi, k + 0, 16);
            const int n1 = __shfl(pi, k + 1, 16);
            const int n2 = __shfl(pi, k + 2, 16);
            const int n3 = __shfl(pi, k + 3, 16);
            const float* p0 = fc + ((size_t)n0 << 8) + li * 16;
            const float* p1 = fc + ((size_t)n1 << 8) + li * 16;
            const float* p2 = fc + ((size_t)n2 << 8) + li * 16;
            const float* p3 = fc + ((size_t)n3 << 8) + li * 16;
            // 16 independent float4 gathers in flight
            const float4 a0 = LD4(p0), a1 = LD4(p0 + 4), a2 = LD4(p0 + 8), a3 = LD4(p0 + 12);
            const float4 b0 = LD4(p1), b1 = LD4(p1 + 4), b2 = LD4(p1 + 8), b3 = LD4(p1 + 12);
            const float4 c0 = LD4(p2), c1 = LD4(p2 + 4), c2 = LD4(p2 + 8), c3 = LD4(p2 + 12);
            const float4 d0 = LD4(p3), d1 = LD4(p3 + 4), d2 = LD4(p3 + 8), d3 = LD4(p3 + 12);
            // codes/masks broadcast overlaps gather latency
            const float y0 = __shfl(pc, k + 0, 16), m0 = __shfl(pm, k + 0, 16);
            const float y1 = __shfl(pc, k + 1, 16), m1 = __shfl(pm, k + 1, 16);
            const float y2 = __shfl(pc, k + 2, 16), m2 = __shfl(pm, k + 2, 16);
            const float y3 = __shfl(pc, k + 3, 16), m3 = __shfl(pm, k + 3, 16);

            float q0 = dot16(e0, e1, e2, e3, a0, a1, a2, a3);
            float q1 = dot16(e0, e1, e2, e3, b0, b1, b2, b3);
            float q2 = dot16(e0, e1, e2, e3, c0, c1, c2, c3);
            float q3 = dot16(e0, e1, e2, e3, d0, d1, d2, d3);
            q0 = redgrp16(q0); q1 = redgrp16(q1); q2 = redgrp16(q2); q3 = redgrp16(q3);

            bce_acc += bce_term(q0, y0, m0);
            bce_acc += bce_term(q1, y1, m1);
            bce_acc += bce_term(q2, y2, m2);
            bce_acc += bce_term(q3, y3, m3);
        }
    }

    // bce_acc is a full copy within each group -> 2 xor stages sum the 4 groups
    bce_acc += __shfl_xor(bce_acc, 16, 64);
    bce_acc += __shfl_xor(bce_acc, 32, 64);
    // cnt_acc differs per lane -> full 6-stage butterfly
    #pragma unroll
    for (int off = 32; off > 0; off >>= 1)
        cnt_acc += __shfl_xor(cnt_acc, off, 64);

    __shared__ float s_b[4], s_c[4];
    __shared__ int s_last;
    if (lane == 0) { s_b[wid] = bce_acc; s_c[wid] = cnt_acc; }   // no scale: exact sum
    __syncthreads();
    if (threadIdx.x == 0) {
        const int nw = blockDim.x >> 6;
        float b = 0.0f, c = 0.0f;
        for (int i = 0; i < nw; ++i) { b += s_b[i]; c += s_c[i]; }
        partials[blockIdx.x] = make_float2(b, c);
        __threadfence();
        const unsigned int old = atomicAdd(count, 1u);
        s_last = (old == (unsigned int)(nblocks - 1)) ? 1 : 0;
    }
    __syncthreads();

    if (s_last) {
        __threadfence();
        const volatile float* vp = (const volatile float*)partials;
        double b = 0.0, c = 0.0;
        for (int i = threadIdx.x; i < nblocks; i += blockDim.x) {
            b += (double)vp[2 * i];
            c += (double)vp[2 * i + 1];
        }
        __shared__ double db[256], dc[256];
        db[threadIdx.x] = b; dc[threadIdx.x] = c;
        __syncthreads();
        for (int s = 128; s > 0; s >>= 1) {
            if (threadIdx.x < (unsigned)s) {
                db[threadIdx.x] += db[threadIdx.x + s];
                dc[threadIdx.x] += dc[threadIdx.x + s];
            }
            __syncthreads();
        }
        if (threadIdx.x == 0) out[0] = (float)(db[0] / dc[0]);
    }
}

extern "C" void kernel_launch(void* const* d_in, const int* in_sizes, int n_in,
                              void* d_out, int out_size, void* d_ws, size_t ws_size,
                              hipStream_t stream) {
    const float* emb        = (const float*)d_in[0];
    const float* fc         = (const float*)d_in[1];
    const int*   target     = (const int*)d_in[2];
    const int*   path_idx   = (const int*)d_in[3];
    const float* path_codes = (const float*)d_in[4];
    const float* path_mask  = (const float*)d_in[5];

    const int N = in_sizes[2];
    const int V = in_sizes[1] / 256 + 1;
    const int L = in_sizes[3] / V;

    unsigned int* count    = (unsigned int*)d_ws;
    float2*       partials = (float2*)((char*)d_ws + 256);
    float*        out      = (float*)d_out;

    const int block = 256;                       // 4 waves, 16 rows per block
    int nblocks = (N + 15) / 16;
    if (nblocks < 1) nblocks = 1;

    hipMemsetAsync(count, 0, sizeof(unsigned int), stream);
    hs_main<<<nblocks, block, 0, stream>>>(emb, fc, target, path_idx, path_codes,
                                           path_mask, count, partials, out,
                                           N, L, nblocks);
}